// Round 7
// baseline (295.072 us; speedup 1.0000x reference)
//
#include <hip/hip_runtime.h>
#include <hip/hip_bf16.h>
#include <math.h>

typedef unsigned short u16;
typedef __attribute__((ext_vector_type(8))) short bf16x8;
typedef __attribute__((ext_vector_type(4))) float f32x4;

#define BATCH 4
#define TSEQ  2048
#define HEADS 16
#define DK    64
#define EMB   1024
#define MROWS 8192            // B*T
#define NQKV  3072
#define PHT   ((size_t)MROWS * EMB)   // 8388608 elems per Q/K/V plane

__device__ __forceinline__ u16 f2bf(float f) {
    union { float f; unsigned int i; } v;
    v.f = f;
    unsigned int x = v.i;
    return (u16)((x + 0x7FFFu + ((x >> 16) & 1u)) >> 16);  // RNE
}

// packed 2xfp32 -> 2xbf16 (RNE) in one u32
__device__ __forceinline__ unsigned int pk2bf(float a, float b) {
    float2 f2; f2.x = a; f2.y = b;
    union { __hip_bfloat162 h; unsigned int u; } cv;
    cv.h = __float22bfloat162_rn(f2);
    return cv.u;
}

// async 16B global->LDS (dest = wave-uniform base + lane*16)
__device__ __forceinline__ void gl2lds16(const u16* g, u16* l) {
    __builtin_amdgcn_global_load_lds(
        (const __attribute__((address_space(1))) unsigned int*)g,
        (__attribute__((address_space(3))) unsigned int*)l, 16, 0, 0);
}

// ---------------------------------------------------------------------------
// prep: fp32 -> bf16 convert (X); both weight transposes in ONE launch
// ---------------------------------------------------------------------------
__global__ __launch_bounds__(256) void convert_x(const float* __restrict__ X,
                                                 u16* __restrict__ Xb) {
    int i = (blockIdx.x * 256 + threadIdx.x) * 4;
    float4 v = *(const float4*)&X[i];
    ushort4 o;
    o.x = f2bf(v.x); o.y = f2bf(v.y); o.z = f2bf(v.z); o.w = f2bf(v.w);
    *(ushort4*)&Xb[i] = o;
}

// bx < 96 -> Wqkv (N=3072); else Wo (N=1024). K=1024 for both.
__global__ __launch_bounds__(256) void transpose_both(const float* __restrict__ Wqkv,
                                                      const float* __restrict__ Wo,
                                                      u16* __restrict__ Wt,
                                                      u16* __restrict__ Wot) {
    __shared__ float tile[32][33];
    const int tx = threadIdx.x & 31, ty = threadIdx.x >> 5;  // 32 x 8
    const int K = 1024;
    const float* W;
    u16* D;
    int N, bx;
    if (blockIdx.x < 96) { W = Wqkv; D = Wt; N = 3072; bx = blockIdx.x; }
    else                 { W = Wo;   D = Wot; N = 1024; bx = blockIdx.x - 96; }
    const int by = blockIdx.y;
#pragma unroll
    for (int s = 0; s < 4; s++)
        tile[ty + 8 * s][tx] = W[(size_t)(by * 32 + ty + 8 * s) * N + bx * 32 + tx];
    __syncthreads();
#pragma unroll
    for (int s = 0; s < 4; s++)
        D[(size_t)(bx * 32 + ty + 8 * s) * K + by * 32 + tx] = f2bf(tile[tx][ty + 8 * s]);
}

// ---------------------------------------------------------------------------
// MFMA GEMM core: BK=64 (16 iters @ K=1024 -> half the barriers of BK=32).
// 4 waves, wave does 64x64 via 4x4 MFMA 16x16x32. LDS 2x16KB, 4 blocks/CU.
// ---------------------------------------------------------------------------
template <int KDIM>
__device__ __forceinline__ void gemm_core(const u16* __restrict__ A,
                                          const u16* __restrict__ Bt,
                                          u16* As, u16* Bs,
                                          int m0, int n0, int wm, int wn,
                                          int tid, int lo, int quad,
                                          f32x4 (&acc)[4][4]) {
    for (int k0 = 0; k0 < KDIM; k0 += 64) {
        __syncthreads();
#pragma unroll
        for (int c = 0; c < 4; c++) {
            int chunk = c * 256 + tid;
            int row = chunk >> 3, p = chunk & 7;   // 8 chunks per 64-elem row
            int pg = p ^ (row & 7);
            gl2lds16(A + (size_t)(m0 + row) * KDIM + k0 + pg * 8, As + chunk * 8);
            gl2lds16(Bt + (size_t)(n0 + row) * KDIM + k0 + pg * 8, Bs + chunk * 8);
        }
        __syncthreads();
#pragma unroll
        for (int kk = 0; kk < 2; kk++) {
            bf16x8 af[4], bw[4];
#pragma unroll
            for (int i = 0; i < 4; i++) {
                int r = wm + i * 16 + lo;
                int ch = (kk * 4 + quad) ^ (r & 7);
                af[i] = *(const bf16x8*)&As[r * 64 + ch * 8];
            }
#pragma unroll
            for (int j = 0; j < 4; j++) {
                int r = wn + j * 16 + lo;
                int ch = (kk * 4 + quad) ^ (r & 7);
                bw[j] = *(const bf16x8*)&Bs[r * 64 + ch * 8];
            }
#pragma unroll
            for (int i = 0; i < 4; i++)
#pragma unroll
                for (int j = 0; j < 4; j++)
                    acc[i][j] = __builtin_amdgcn_mfma_f32_16x16x32_bf16(
                        af[i], bw[j], acc[i][j], 0, 0, 0);
        }
    }
}

// GEMM1: qkv = Xb @ Wqkv_t^T + b.  Q scattered to [bh][t][d] PRE-SCALED by
// (1/sqrt(dk))*log2(e); K to [bh][t][d]; V TRANSPOSED to [bh][d][t].
__global__ __launch_bounds__(256) void gemm1_mfma(const u16* __restrict__ A,
                                                  const u16* __restrict__ Bt,
                                                  const float* __restrict__ bias,
                                                  u16* __restrict__ qkv) {
    __shared__ u16 As[128 * 64];
    __shared__ u16 Bs[128 * 64];
    const int tid = threadIdx.x;
    const int lane = tid & 63, wv = tid >> 6;
    const int lo = lane & 15, quad = lane >> 4;
    const int m0 = blockIdx.y * 128, n0 = blockIdx.x * 128;
    const int wm = (wv >> 1) * 64, wn = (wv & 1) * 64;
    const float scale2 = 0.18033688011112042f;  // (1/8) * log2(e)
    f32x4 acc[4][4] = {};

    gemm_core<1024>(A, Bt, As, Bs, m0, n0, wm, wn, tid, lo, quad, acc);

    const int whichw = (n0 + wn) >> 10;   // uniform per wave (0=Q,1=K,2=V)
    if (whichw == 2) {
        // V plane: [bh][d][t], pack 4 consecutive t (C-layout rows) per store
#pragma unroll
        for (int i = 0; i < 4; i++) {
            int mb = m0 + wm + i * 16 + quad * 4;
            int b = mb >> 11, t = mb & 2047;
#pragma unroll
            for (int j = 0; j < 4; j++) {
                int n = n0 + wn + j * 16 + lo;
                int rem = n & 1023;
                int h = rem >> 6, d = rem & 63;
                float bn = bias[n];
                ushort4 o;
                o.x = f2bf(acc[i][j][0] + bn);
                o.y = f2bf(acc[i][j][1] + bn);
                o.z = f2bf(acc[i][j][2] + bn);
                o.w = f2bf(acc[i][j][3] + bn);
                *(ushort4*)&qkv[2 * PHT +
                                (((size_t)(b * HEADS + h) * DK + d) * TSEQ + t)] = o;
            }
        }
    } else {
        const float sc = (whichw == 0) ? scale2 : 1.0f;
#pragma unroll
        for (int i = 0; i < 4; i++) {
#pragma unroll
            for (int r = 0; r < 4; r++) {
                int m = m0 + wm + i * 16 + quad * 4 + r;
                int b = m >> 11, t = m & 2047;
#pragma unroll
                for (int j = 0; j < 4; j++) {
                    int n = n0 + wn + j * 16 + lo;
                    float v = (acc[i][j][r] + bias[n]) * sc;
                    int rem = n & 1023;
                    int h = rem >> 6, d = rem & 63;
                    qkv[(size_t)whichw * PHT +
                        (((size_t)(b * HEADS + h) * TSEQ + t) * DK + d)] = f2bf(v);
                }
            }
        }
    }
}

// GEMM2: out = AO @ Wo_t^T + b (fp32 out)
__global__ __launch_bounds__(256) void gemm2_mfma(const u16* __restrict__ A,
                                                  const u16* __restrict__ Bt,
                                                  const float* __restrict__ bias,
                                                  float* __restrict__ out) {
    __shared__ u16 As[128 * 64];
    __shared__ u16 Bs[128 * 64];
    const int tid = threadIdx.x;
    const int lane = tid & 63, wv = tid >> 6;
    const int lo = lane & 15, quad = lane >> 4;
    const int m0 = blockIdx.y * 128, n0 = blockIdx.x * 128;
    const int wm = (wv >> 1) * 64, wn = (wv & 1) * 64;
    f32x4 acc[4][4] = {};

    gemm_core<1024>(A, Bt, As, Bs, m0, n0, wm, wn, tid, lo, quad, acc);

#pragma unroll
    for (int i = 0; i < 4; i++) {
#pragma unroll
        for (int r = 0; r < 4; r++) {
            int m = m0 + wm + i * 16 + quad * 4 + r;
#pragma unroll
            for (int j = 0; j < 4; j++) {
                int n = n0 + wn + j * 16 + lo;
                out[(size_t)m * EMB + n] = acc[i][j][r] + bias[n];
            }
        }
    }
}

// ---------------------------------------------------------------------------
// MFMA flash attention v4: no-max softmax + DOUBLE-BUFFERED K/V prefetch.
// Grid (8 pairs, B*H), 256 threads. Block p does q-tiles {p, 15-p} -> 17
// k-iterations of 128 keys. One barrier per iteration; loads for kt+1 are
// issued right after it into the other buffer and fly across kt's compute.
// Q (pre-scaled), K: [bh][t][d].  V: [bh][d][t].  Out: [B][T][H][64] bf16.
// LDS 80KB: Ks[2] | Vt[2] | Rr (Q staging overlaid with per-wave P).
// ---------------------------------------------------------------------------
__global__ __launch_bounds__(256, 2) void attn_mfma(const u16* __restrict__ Qg,
                                                    const u16* __restrict__ Kg,
                                                    const u16* __restrict__ Vg,
                                                    u16* __restrict__ AO) {
    __shared__ u16 pool[5 * 8192];
    u16* Rr = pool + 4 * 8192;   // Q staging (128x64) then per-wave P (32x64)

    const int tid = threadIdx.x;
    const int lane = tid & 63, wv = tid >> 6;
    const int lo = lane & 15, quad = lane >> 4;
    const int pair = blockIdx.x, bh = blockIdx.y;
    const size_t base = (size_t)bh * TSEQ * DK;
    const int b = bh >> 4, h = bh & 15;
    const bf16x8 onesf = {0x3F80, 0x3F80, 0x3F80, 0x3F80,
                          0x3F80, 0x3F80, 0x3F80, 0x3F80};

    // stage K(kt2) and V^T(kt2) into buffer bufsel
    auto stageKV = [&](int kt2, int bufsel) {
        u16* Kd = pool + bufsel * 8192;
        u16* Vd = pool + 2 * 8192 + bufsel * 8192;
#pragma unroll
        for (int c = 0; c < 4; c++) {
            int chunk = c * 256 + tid;
            int row = chunk >> 3, p = chunk & 7;
            int pg = p ^ (row & 7);
            gl2lds16(Kg + base + (size_t)(kt2 * 128 + row) * DK + pg * 8,
                     Kd + chunk * 8);
        }
#pragma unroll
        for (int c = 0; c < 4; c++) {
            int chunk = c * 256 + tid;
            int row = chunk >> 4, p = chunk & 15;
            int pg = p ^ (row & 15);
            gl2lds16(Vg + base + (size_t)row * TSEQ + kt2 * 128 + pg * 8,
                     Vd + chunk * 8);
        }
    };

    for (int qi = 0; qi < 2; qi++) {
        const int qt = qi ? (15 - pair) : pair;
        const int q0 = qt * 128;

        __syncthreads();  // prior tile's Ps/Ks/Vt readers done
        // stage Q tile (128x64) into Rr + prologue K0/V0 into buf0
#pragma unroll
        for (int c = 0; c < 4; c++) {
            int chunk = c * 256 + tid;
            int row = chunk >> 3, p = chunk & 7;
            int pg = p ^ (row & 7);
            gl2lds16(Qg + base + (size_t)(q0 + row) * DK + pg * 8, Rr + chunk * 8);
        }
        stageKV(0, 0);
        __syncthreads();  // Q + K0/V0 ready

        // hoist Q B-fragments (kt-invariant; wave-local rows of Rr)
        bf16x8 bq[2][2];
#pragma unroll
        for (int i = 0; i < 2; i++)
#pragma unroll
            for (int hh = 0; hh < 2; hh++) {
                int row = wv * 32 + i * 16 + lo;
                int ch = (hh * 4 + quad) ^ (row & 7);
                bq[i][hh] = *(const bf16x8*)&Rr[row * 64 + ch * 8];
            }

        f32x4 O[2][5] = {};   // [i][0..3 = d-tiles, 4 = row-sum l]

        for (int kt = 0; kt <= qt; kt++) {
            const int cur = kt & 1;
            if (kt) __syncthreads();          // all waves done kt-1; drains prefetch(kt)
            if (kt < qt) stageKV(kt + 1, cur ^ 1);   // flies across kt's compute
            const u16* Ksc = pool + cur * 8192;
            const u16* Vtc = pool + 2 * 8192 + cur * 8192;

            const bool diag = (kt == qt);
            u16* Ps = Rr + wv * 2048;   // per-wave 32 rows x 64 keys (half-tile)

#pragma unroll
            for (int jh = 0; jh < 2; jh++) {
                // S^T = K @ Q^T for 64-key half: st[j2][i]
                f32x4 st[4][2] = {};
#pragma unroll
                for (int hh = 0; hh < 2; hh++) {
#pragma unroll
                    for (int j2 = 0; j2 < 4; j2++) {
                        int row = (jh * 4 + j2) * 16 + lo;
                        int ch = (hh * 4 + quad) ^ (row & 7);
                        bf16x8 ak = *(const bf16x8*)&Ksc[row * 64 + ch * 8];
                        st[j2][0] = __builtin_amdgcn_mfma_f32_16x16x32_bf16(
                            ak, bq[0][hh], st[j2][0], 0, 0, 0);
                        st[j2][1] = __builtin_amdgcn_mfma_f32_16x16x32_bf16(
                            ak, bq[1][hh], st[j2][1], 0, 0, 0);
                    }
                }
                // P = exp2(S^T) (no max), causal-mask diagonal tile only,
                // packed b64 write to Ps[row=qrow][key]
#pragma unroll
                for (int j2 = 0; j2 < 4; j2++) {
#pragma unroll
                    for (int i = 0; i < 2; i++) {
                        float e[4];
#pragma unroll
                        for (int r = 0; r < 4; r++)
                            e[r] = __builtin_amdgcn_exp2f(st[j2][i][r]);
                        if (diag) {
                            int qr = q0 + wv * 32 + i * 16 + lo;
                            int kb = kt * 128 + (jh * 4 + j2) * 16 + quad * 4;
#pragma unroll
                            for (int r = 0; r < 4; r++)
                                if (kb + r > qr) e[r] = 0.f;
                        }
                        uint2 w;
                        w.x = pk2bf(e[0], e[1]);
                        w.y = pk2bf(e[2], e[3]);
                        int rowl = i * 16 + lo;
                        int chp = (2 * j2 + (quad >> 1)) ^ (lo & 7);
                        *(uint2*)&Ps[rowl * 64 + chp * 8 + (quad & 1) * 4] = w;
                    }
                }
                // O += P @ V for this 64-key half (2 MFMA k-steps)
#pragma unroll
                for (int hp = 0; hp < 2; hp++) {
                    bf16x8 ap[2], bv[4];
#pragma unroll
                    for (int i = 0; i < 2; i++) {
                        int rowl = i * 16 + lo;
                        int ch = (4 * hp + quad) ^ (lo & 7);
                        ap[i] = *(const bf16x8*)&Ps[rowl * 64 + ch * 8];
                    }
#pragma unroll
                    for (int jn = 0; jn < 4; jn++) {
                        int vrow = jn * 16 + lo;   // d index
                        int ch = (8 * jh + 4 * hp + quad) ^ (vrow & 15);
                        bv[jn] = *(const bf16x8*)&Vtc[vrow * 128 + ch * 8];
                    }
#pragma unroll
                    for (int i = 0; i < 2; i++) {
#pragma unroll
                        for (int jn = 0; jn < 4; jn++)
                            O[i][jn] = __builtin_amdgcn_mfma_f32_16x16x32_bf16(
                                ap[i], bv[jn], O[i][jn], 0, 0, 0);
                        O[i][4] = __builtin_amdgcn_mfma_f32_16x16x32_bf16(
                            ap[i], onesf, O[i][4], 0, 0, 0);
                    }
                }
            }
        }

        // epilogue: normalize by l, store [B][T][H][DK] bf16
#pragma unroll
        for (int i = 0; i < 2; i++)
#pragma unroll
            for (int r = 0; r < 4; r++) {
                int qrow = q0 + wv * 32 + i * 16 + quad * 4 + r;
                float inv = 1.f / O[i][4][r];
#pragma unroll
                for (int jn = 0; jn < 4; jn++) {
                    int d = jn * 16 + lo;
                    AO[(((size_t)b * TSEQ + qrow) * HEADS + h) * DK + d] =
                        f2bf(O[i][jn][r] * inv);
                }
            }
    }
}

// ---------------------------------------------------------------------------
extern "C" void kernel_launch(void* const* d_in, const int* in_sizes, int n_in,
                              void* d_out, int out_size, void* d_ws, size_t ws_size,
                              hipStream_t stream) {
    const float* x    = (const float*)d_in[0];
    const float* Wqkv = (const float*)d_in[1];
    const float* bqkv = (const float*)d_in[2];
    const float* Wo   = (const float*)d_in[3];
    const float* bo   = (const float*)d_in[4];
    float* out = (float*)d_out;

    // workspace layout (u16 elems): [Xb 8.4M | Wt 3.1M | Wot 1M | QKV 25.2M]
    u16* Xb  = (u16*)d_ws;
    u16* Wt  = Xb + PHT;                    // [3072][1024]
    u16* Wot = Wt + (size_t)NQKV * EMB;     // [1024][1024]
    u16* qkv = Wot + (size_t)EMB * EMB;     // Q,K: [bh][t][d]; V: [bh][d][t]
    u16* AO  = Xb;                          // overlay: Xb dead after gemm1

    convert_x<<<MROWS * EMB / 1024, 256, 0, stream>>>(x, Xb);
    transpose_both<<<dim3(96 + 32, 32), 256, 0, stream>>>(Wqkv, Wo, Wt, Wot);

    gemm1_mfma<<<dim3(NQKV / 128, MROWS / 128), 256, 0, stream>>>(Xb, Wt, bqkv, qkv);
    attn_mfma<<<dim3(8, BATCH * HEADS), 256, 0, stream>>>(
        qkv, qkv + PHT, qkv + 2 * PHT, AO);
    gemm2_mfma<<<dim3(EMB / 128, MROWS / 128), 256, 0, stream>>>(AO, Wot, bo, out);
}

// Round 8
// 255.226 us; speedup vs baseline: 1.1561x; 1.1561x over previous
//
#include <hip/hip_runtime.h>
#include <hip/hip_bf16.h>
#include <math.h>

typedef unsigned short u16;
typedef __attribute__((ext_vector_type(8))) short bf16x8;
typedef __attribute__((ext_vector_type(4))) float f32x4;

#define BATCH 4
#define TSEQ  2048
#define HEADS 16
#define DK    64
#define EMB   1024
#define MROWS 8192            // B*T
#define NQKV  3072
#define PHT   ((size_t)MROWS * EMB)   // 8388608 elems per Q/K/V plane

__device__ __forceinline__ u16 f2bf(float f) {
    union { float f; unsigned int i; } v;
    v.f = f;
    unsigned int x = v.i;
    return (u16)((x + 0x7FFFu + ((x >> 16) & 1u)) >> 16);  // RNE
}

// packed 2xfp32 -> 2xbf16 (RNE) in one u32
__device__ __forceinline__ unsigned int pk2bf(float a, float b) {
    float2 f2; f2.x = a; f2.y = b;
    union { __hip_bfloat162 h; unsigned int u; } cv;
    cv.h = __float22bfloat162_rn(f2);
    return cv.u;
}

// async 16B global->LDS (dest = wave-uniform base + lane*16)
__device__ __forceinline__ void gl2lds16(const u16* g, u16* l) {
    __builtin_amdgcn_global_load_lds(
        (const __attribute__((address_space(1))) unsigned int*)g,
        (__attribute__((address_space(3))) unsigned int*)l, 16, 0, 0);
}

// ---------------------------------------------------------------------------
// prep: fp32 -> bf16 convert (X); both weight transposes in ONE launch
// ---------------------------------------------------------------------------
__global__ __launch_bounds__(256) void convert_x(const float* __restrict__ X,
                                                 u16* __restrict__ Xb) {
    int i = (blockIdx.x * 256 + threadIdx.x) * 4;
    float4 v = *(const float4*)&X[i];
    ushort4 o;
    o.x = f2bf(v.x); o.y = f2bf(v.y); o.z = f2bf(v.z); o.w = f2bf(v.w);
    *(ushort4*)&Xb[i] = o;
}

// bx < 96 -> Wqkv (N=3072); else Wo (N=1024). K=1024 for both.
__global__ __launch_bounds__(256) void transpose_both(const float* __restrict__ Wqkv,
                                                      const float* __restrict__ Wo,
                                                      u16* __restrict__ Wt,
                                                      u16* __restrict__ Wot) {
    __shared__ float tile[32][33];
    const int tx = threadIdx.x & 31, ty = threadIdx.x >> 5;  // 32 x 8
    const int K = 1024;
    const float* W;
    u16* D;
    int N, bx;
    if (blockIdx.x < 96) { W = Wqkv; D = Wt; N = 3072; bx = blockIdx.x; }
    else                 { W = Wo;   D = Wot; N = 1024; bx = blockIdx.x - 96; }
    const int by = blockIdx.y;
#pragma unroll
    for (int s = 0; s < 4; s++)
        tile[ty + 8 * s][tx] = W[(size_t)(by * 32 + ty + 8 * s) * N + bx * 32 + tx];
    __syncthreads();
#pragma unroll
    for (int s = 0; s < 4; s++)
        D[(size_t)(bx * 32 + ty + 8 * s) * K + by * 32 + tx] = f2bf(tile[tx][ty + 8 * s]);
}

// ---------------------------------------------------------------------------
// MFMA GEMM core (round-6 BK=32 version: VGPR 128, 4 waves/SIMD — do NOT
// raise BK: BK=64 pushed VGPR to 132 -> occupancy cliff, 84->124 us).
// 4 waves, wave does 64x64 via 4x4 MFMA 16x16x32. LDS 2x8KB.
// ---------------------------------------------------------------------------
template <int KDIM>
__device__ __forceinline__ void gemm_core(const u16* __restrict__ A,
                                          const u16* __restrict__ Bt,
                                          u16* As, u16* Bs,
                                          int m0, int n0, int wm, int wn,
                                          int tid, int lo, int quad,
                                          f32x4 (&acc)[4][4]) {
    for (int k0 = 0; k0 < KDIM; k0 += 32) {
        __syncthreads();
#pragma unroll
        for (int c = 0; c < 2; c++) {
            int chunk = c * 256 + tid;
            int row = chunk >> 2, p = chunk & 3;
            int pg = p ^ ((row >> 1) & 3);
            gl2lds16(A + (size_t)(m0 + row) * KDIM + k0 + pg * 8, As + chunk * 8);
            gl2lds16(Bt + (size_t)(n0 + row) * KDIM + k0 + pg * 8, Bs + chunk * 8);
        }
        __syncthreads();
        bf16x8 af[4], bw[4];
#pragma unroll
        for (int i = 0; i < 4; i++) {
            int r = wm + i * 16 + lo;
            int pp = quad ^ ((r >> 1) & 3);
            af[i] = *(const bf16x8*)&As[r * 32 + pp * 8];
        }
#pragma unroll
        for (int j = 0; j < 4; j++) {
            int r = wn + j * 16 + lo;
            int pp = quad ^ ((r >> 1) & 3);
            bw[j] = *(const bf16x8*)&Bs[r * 32 + pp * 8];
        }
#pragma unroll
        for (int i = 0; i < 4; i++)
#pragma unroll
            for (int j = 0; j < 4; j++)
                acc[i][j] = __builtin_amdgcn_mfma_f32_16x16x32_bf16(
                    af[i], bw[j], acc[i][j], 0, 0, 0);
    }
}

// GEMM1: qkv = Xb @ Wqkv_t^T + b.  Q scattered to [bh][t][d] PRE-SCALED by
// (1/sqrt(dk))*log2(e); K to [bh][t][d]; V TRANSPOSED to [bh][d][t].
__global__ __launch_bounds__(256) void gemm1_mfma(const u16* __restrict__ A,
                                                  const u16* __restrict__ Bt,
                                                  const float* __restrict__ bias,
                                                  u16* __restrict__ qkv) {
    __shared__ u16 As[128 * 32];
    __shared__ u16 Bs[128 * 32];
    const int tid = threadIdx.x;
    const int lane = tid & 63, wv = tid >> 6;
    const int lo = lane & 15, quad = lane >> 4;
    const int m0 = blockIdx.y * 128, n0 = blockIdx.x * 128;
    const int wm = (wv >> 1) * 64, wn = (wv & 1) * 64;
    const float scale2 = 0.18033688011112042f;  // (1/8) * log2(e)
    f32x4 acc[4][4] = {};

    gemm_core<1024>(A, Bt, As, Bs, m0, n0, wm, wn, tid, lo, quad, acc);

    const int whichw = (n0 + wn) >> 10;   // uniform per wave (0=Q,1=K,2=V)
    if (whichw == 2) {
        // V plane: [bh][d][t], pack 4 consecutive t (C-layout rows) per store
#pragma unroll
        for (int i = 0; i < 4; i++) {
            int mb = m0 + wm + i * 16 + quad * 4;
            int b = mb >> 11, t = mb & 2047;
#pragma unroll
            for (int j = 0; j < 4; j++) {
                int n = n0 + wn + j * 16 + lo;
                int rem = n & 1023;
                int h = rem >> 6, d = rem & 63;
                float bn = bias[n];
                ushort4 o;
                o.x = f2bf(acc[i][j][0] + bn);
                o.y = f2bf(acc[i][j][1] + bn);
                o.z = f2bf(acc[i][j][2] + bn);
                o.w = f2bf(acc[i][j][3] + bn);
                *(ushort4*)&qkv[2 * PHT +
                                (((size_t)(b * HEADS + h) * DK + d) * TSEQ + t)] = o;
            }
        }
    } else {
        const float sc = (whichw == 0) ? scale2 : 1.0f;
#pragma unroll
        for (int i = 0; i < 4; i++) {
#pragma unroll
            for (int r = 0; r < 4; r++) {
                int m = m0 + wm + i * 16 + quad * 4 + r;
                int b = m >> 11, t = m & 2047;
#pragma unroll
                for (int j = 0; j < 4; j++) {
                    int n = n0 + wn + j * 16 + lo;
                    float v = (acc[i][j][r] + bias[n]) * sc;
                    int rem = n & 1023;
                    int h = rem >> 6, d = rem & 63;
                    qkv[(size_t)whichw * PHT +
                        (((size_t)(b * HEADS + h) * TSEQ + t) * DK + d)] = f2bf(v);
                }
            }
        }
    }
}

// GEMM2: out = AO @ Wo_t^T + b (fp32 out)
__global__ __launch_bounds__(256) void gemm2_mfma(const u16* __restrict__ A,
                                                  const u16* __restrict__ Bt,
                                                  const float* __restrict__ bias,
                                                  float* __restrict__ out) {
    __shared__ u16 As[128 * 32];
    __shared__ u16 Bs[128 * 32];
    const int tid = threadIdx.x;
    const int lane = tid & 63, wv = tid >> 6;
    const int lo = lane & 15, quad = lane >> 4;
    const int m0 = blockIdx.y * 128, n0 = blockIdx.x * 128;
    const int wm = (wv >> 1) * 64, wn = (wv & 1) * 64;
    f32x4 acc[4][4] = {};

    gemm_core<1024>(A, Bt, As, Bs, m0, n0, wm, wn, tid, lo, quad, acc);

#pragma unroll
    for (int i = 0; i < 4; i++) {
#pragma unroll
        for (int r = 0; r < 4; r++) {
            int m = m0 + wm + i * 16 + quad * 4 + r;
#pragma unroll
            for (int j = 0; j < 4; j++) {
                int n = n0 + wn + j * 16 + lo;
                out[(size_t)m * EMB + n] = acc[i][j][r] + bias[n];
            }
        }
    }
}

// ---------------------------------------------------------------------------
// MFMA flash attention v4: no-max softmax + double-buffered K/V prefetch.
// Grid (8 pairs, B*H), 256 threads. Block p does q-tiles {p, 15-p} -> 17
// k-iterations of 128 keys. One barrier per iteration; loads for kt+1 fly
// across kt's compute into the other buffer.
// Q (pre-scaled), K: [bh][t][d].  V: [bh][d][t].  Out: [B][T][H][64] bf16.
// LDS 80KB: Ks[2] | Vt[2] | Rr (Q staging overlaid with per-wave P).
// ---------------------------------------------------------------------------
__global__ __launch_bounds__(256, 2) void attn_mfma(const u16* __restrict__ Qg,
                                                    const u16* __restrict__ Kg,
                                                    const u16* __restrict__ Vg,
                                                    u16* __restrict__ AO) {
    __shared__ u16 pool[5 * 8192];
    u16* Rr = pool + 4 * 8192;   // Q staging (128x64) then per-wave P (32x64)

    const int tid = threadIdx.x;
    const int lane = tid & 63, wv = tid >> 6;
    const int lo = lane & 15, quad = lane >> 4;
    const int pair = blockIdx.x, bh = blockIdx.y;
    const size_t base = (size_t)bh * TSEQ * DK;
    const int b = bh >> 4, h = bh & 15;
    const bf16x8 onesf = {0x3F80, 0x3F80, 0x3F80, 0x3F80,
                          0x3F80, 0x3F80, 0x3F80, 0x3F80};

    // stage K(kt2) and V^T(kt2) into buffer bufsel
    auto stageKV = [&](int kt2, int bufsel) {
        u16* Kd = pool + bufsel * 8192;
        u16* Vd = pool + 2 * 8192 + bufsel * 8192;
#pragma unroll
        for (int c = 0; c < 4; c++) {
            int chunk = c * 256 + tid;
            int row = chunk >> 3, p = chunk & 7;
            int pg = p ^ (row & 7);
            gl2lds16(Kg + base + (size_t)(kt2 * 128 + row) * DK + pg * 8,
                     Kd + chunk * 8);
        }
#pragma unroll
        for (int c = 0; c < 4; c++) {
            int chunk = c * 256 + tid;
            int row = chunk >> 4, p = chunk & 15;
            int pg = p ^ (row & 15);
            gl2lds16(Vg + base + (size_t)row * TSEQ + kt2 * 128 + pg * 8,
                     Vd + chunk * 8);
        }
    };

    for (int qi = 0; qi < 2; qi++) {
        const int qt = qi ? (15 - pair) : pair;
        const int q0 = qt * 128;

        __syncthreads();  // prior tile's Ps/Ks/Vt readers done
        // stage Q tile (128x64) into Rr + prologue K0/V0 into buf0
#pragma unroll
        for (int c = 0; c < 4; c++) {
            int chunk = c * 256 + tid;
            int row = chunk >> 3, p = chunk & 7;
            int pg = p ^ (row & 7);
            gl2lds16(Qg + base + (size_t)(q0 + row) * DK + pg * 8, Rr + chunk * 8);
        }
        stageKV(0, 0);
        __syncthreads();  // Q + K0/V0 ready

        // hoist Q B-fragments (kt-invariant; wave-local rows of Rr)
        bf16x8 bq[2][2];
#pragma unroll
        for (int i = 0; i < 2; i++)
#pragma unroll
            for (int hh = 0; hh < 2; hh++) {
                int row = wv * 32 + i * 16 + lo;
                int ch = (hh * 4 + quad) ^ (row & 7);
                bq[i][hh] = *(const bf16x8*)&Rr[row * 64 + ch * 8];
            }

        f32x4 O[2][5] = {};   // [i][0..3 = d-tiles, 4 = row-sum l]

        for (int kt = 0; kt <= qt; kt++) {
            const int cur = kt & 1;
            if (kt) __syncthreads();          // all waves done kt-1; drains prefetch(kt)
            if (kt < qt) stageKV(kt + 1, cur ^ 1);   // flies across kt's compute
            const u16* Ksc = pool + cur * 8192;
            const u16* Vtc = pool + 2 * 8192 + cur * 8192;

            const bool diag = (kt == qt);
            u16* Ps = Rr + wv * 2048;   // per-wave 32 rows x 64 keys (half-tile)

#pragma unroll
            for (int jh = 0; jh < 2; jh++) {
                // S^T = K @ Q^T for 64-key half: st[j2][i]
                f32x4 st[4][2] = {};
#pragma unroll
                for (int hh = 0; hh < 2; hh++) {
#pragma unroll
                    for (int j2 = 0; j2 < 4; j2++) {
                        int row = (jh * 4 + j2) * 16 + lo;
                        int ch = (hh * 4 + quad) ^ (row & 7);
                        bf16x8 ak = *(const bf16x8*)&Ksc[row * 64 + ch * 8];
                        st[j2][0] = __builtin_amdgcn_mfma_f32_16x16x32_bf16(
                            ak, bq[0][hh], st[j2][0], 0, 0, 0);
                        st[j2][1] = __builtin_amdgcn_mfma_f32_16x16x32_bf16(
                            ak, bq[1][hh], st[j2][1], 0, 0, 0);
                    }
                }
                // P = exp2(S^T) (no max), causal-mask diagonal tile only,
                // packed b64 write to Ps[row=qrow][key]
#pragma unroll
                for (int j2 = 0; j2 < 4; j2++) {
#pragma unroll
                    for (int i = 0; i < 2; i++) {
                        float e[4];
#pragma unroll
                        for (int r = 0; r < 4; r++)
                            e[r] = __builtin_amdgcn_exp2f(st[j2][i][r]);
                        if (diag) {
                            int qr = q0 + wv * 32 + i * 16 + lo;
                            int kb = kt * 128 + (jh * 4 + j2) * 16 + quad * 4;
#pragma unroll
                            for (int r = 0; r < 4; r++)
                                if (kb + r > qr) e[r] = 0.f;
                        }
                        uint2 w;
                        w.x = pk2bf(e[0], e[1]);
                        w.y = pk2bf(e[2], e[3]);
                        int rowl = i * 16 + lo;
                        int chp = (2 * j2 + (quad >> 1)) ^ (lo & 7);
                        *(uint2*)&Ps[rowl * 64 + chp * 8 + (quad & 1) * 4] = w;
                    }
                }
                // O += P @ V for this 64-key half (2 MFMA k-steps)
#pragma unroll
                for (int hp = 0; hp < 2; hp++) {
                    bf16x8 ap[2], bv[4];
#pragma unroll
                    for (int i = 0; i < 2; i++) {
                        int rowl = i * 16 + lo;
                        int ch = (4 * hp + quad) ^ (lo & 7);
                        ap[i] = *(const bf16x8*)&Ps[rowl * 64 + ch * 8];
                    }
#pragma unroll
                    for (int jn = 0; jn < 4; jn++) {
                        int vrow = jn * 16 + lo;   // d index
                        int ch = (8 * jh + 4 * hp + quad) ^ (vrow & 15);
                        bv[jn] = *(const bf16x8*)&Vtc[vrow * 128 + ch * 8];
                    }
#pragma unroll
                    for (int i = 0; i < 2; i++) {
#pragma unroll
                        for (int jn = 0; jn < 4; jn++)
                            O[i][jn] = __builtin_amdgcn_mfma_f32_16x16x32_bf16(
                                ap[i], bv[jn], O[i][jn], 0, 0, 0);
                        O[i][4] = __builtin_amdgcn_mfma_f32_16x16x32_bf16(
                            ap[i], onesf, O[i][4], 0, 0, 0);
                    }
                }
            }
        }

        // epilogue: normalize by l, store [B][T][H][DK] bf16
#pragma unroll
        for (int i = 0; i < 2; i++)
#pragma unroll
            for (int r = 0; r < 4; r++) {
                int qrow = q0 + wv * 32 + i * 16 + quad * 4 + r;
                float inv = 1.f / O[i][4][r];
#pragma unroll
                for (int jn = 0; jn < 4; jn++) {
                    int d = jn * 16 + lo;
                    AO[(((size_t)b * TSEQ + qrow) * HEADS + h) * DK + d] =
                        f2bf(O[i][jn][r] * inv);
                }
            }
    }
}

// ---------------------------------------------------------------------------
extern "C" void kernel_launch(void* const* d_in, const int* in_sizes, int n_in,
                              void* d_out, int out_size, void* d_ws, size_t ws_size,
                              hipStream_t stream) {
    const float* x    = (const float*)d_in[0];
    const float* Wqkv = (const float*)d_in[1];
    const float* bqkv = (const float*)d_in[2];
    const float* Wo   = (const float*)d_in[3];
    const float* bo   = (const float*)d_in[4];
    float* out = (float*)d_out;

    // workspace layout (u16 elems): [Xb 8.4M | Wt 3.1M | Wot 1M | QKV 25.2M]
    u16* Xb  = (u16*)d_ws;
    u16* Wt  = Xb + PHT;                    // [3072][1024]
    u16* Wot = Wt + (size_t)NQKV * EMB;     // [1024][1024]
    u16* qkv = Wot + (size_t)EMB * EMB;     // Q,K: [bh][t][d]; V: [bh][d][t]
    u16* AO  = Xb;                          // overlay: Xb dead after gemm1

    convert_x<<<MROWS * EMB / 1024, 256, 0, stream>>>(x, Xb);
    transpose_both<<<dim3(96 + 32, 32), 256, 0, stream>>>(Wqkv, Wo, Wt, Wot);

    gemm1_mfma<<<dim3(NQKV / 128, MROWS / 128), 256, 0, stream>>>(Xb, Wt, bqkv, qkv);
    attn_mfma<<<dim3(8, BATCH * HEADS), 256, 0, stream>>>(
        qkv, qkv + PHT, qkv + 2 * PHT, AO);
    gemm2_mfma<<<dim3(EMB / 128, MROWS / 128), 256, 0, stream>>>(AO, Wot, bo, out);
}